// Round 8
// baseline (370.311 us; speedup 1.0000x reference)
//
#include <hip/hip_runtime.h>
#include <math.h>

#define N_NODES 10000
#define E_EDGES 160000
#define E_TOT   170000   // E + self loops
#define MAXDEG  128
#define MPAD    10112    // 79 * 128

typedef _Float16 f16x8 __attribute__((ext_vector_type(8)));
typedef _Float16 f16x4 __attribute__((ext_vector_type(4)));
typedef _Float16 f16x2 __attribute__((ext_vector_type(2)));
typedef float    f32x4 __attribute__((ext_vector_type(4)));

__device__ __forceinline__ float leaky(float e) { return (e > 0.f) ? e : 0.2f * e; }

// ---------------- graph CSR build (by dst) ----------------
__global__ void count_kernel(const int* __restrict__ ei, int* __restrict__ deg) {
    int e = blockIdx.x * 256 + threadIdx.x;
    if (e >= E_TOT) return;
    int dst = (e < E_EDGES) ? ei[E_EDGES + e] : (e - E_EDGES);
    atomicAdd(&deg[dst], 1);
}

__global__ void scan_kernel(const int* __restrict__ deg, int* __restrict__ rowptr,
                            int* __restrict__ cursor) {
    __shared__ int sums[1024];
    int t = threadIdx.x;
    const int CH = (N_NODES + 1023) / 1024;
    int base = t * CH;
    int s = 0;
    for (int j = 0; j < CH; j++) { int i = base + j; if (i < N_NODES) s += deg[i]; }
    sums[t] = s; __syncthreads();
    for (int off = 1; off < 1024; off <<= 1) {
        int v = (t >= off) ? sums[t - off] : 0;
        __syncthreads();
        sums[t] += v;
        __syncthreads();
    }
    int excl = (t == 0) ? 0 : sums[t - 1];
    for (int j = 0; j < CH; j++) {
        int i = base + j;
        if (i < N_NODES) { rowptr[i] = excl; cursor[i] = excl; excl += deg[i]; }
    }
    if (t == 1023) rowptr[N_NODES] = sums[1023];
}

__global__ void scatter_kernel(const int* __restrict__ ei, int* __restrict__ cursor,
                               int* __restrict__ perm_src) {
    int e = blockIdx.x * 256 + threadIdx.x;
    if (e >= E_TOT) return;
    int src, dst;
    if (e < E_EDGES) { src = ei[e]; dst = ei[E_EDGES + e]; }
    else { src = e - E_EDGES; dst = src; }
    int pos = atomicAdd(&cursor[dst], 1);
    perm_src[pos] = src;
}

// ---------------- all conversions / padding in one kernel ----------------
#define SEG0 (MPAD * 64)               // xh1
#define SEG1 (1024 * 64)               // W1h
#define SEG2 (1024 * 1024)             // W2h
#define SEG3 (768 * 1024)              // W3p (head-padded rows)
#define SEG4 768                        // asp/adp
#define SEG5 ((MPAD - N_NODES) * 1024) // xh zero tail
#define CVT_TOTAL (SEG0 + SEG1 + SEG2 + SEG3 + SEG4 + SEG5)

__global__ void cvt_all(const float* __restrict__ x, const float* __restrict__ W1,
                        const float* __restrict__ W2, const float* __restrict__ W3,
                        const float* __restrict__ as3, const float* __restrict__ ad3,
                        _Float16* __restrict__ xh1, _Float16* __restrict__ W1h,
                        _Float16* __restrict__ W2h, _Float16* __restrict__ W3p,
                        float* __restrict__ asp, float* __restrict__ adp,
                        _Float16* __restrict__ xh) {
    int i = blockIdx.x * 256 + threadIdx.x;
    if (i < SEG0) {
        int r = i >> 6, c = i & 63;
        xh1[i] = (r < N_NODES && c < 50) ? (_Float16)x[r * 50 + c] : (_Float16)0.f;
        return;
    }
    i -= SEG0;
    if (i < SEG1) {
        int r = i >> 6, c = i & 63;
        W1h[i] = (c < 50) ? (_Float16)W1[r * 50 + c] : (_Float16)0.f;
        return;
    }
    i -= SEG1;
    if (i < SEG2) { W2h[i] = (_Float16)W2[i]; return; }
    i -= SEG2;
    if (i < SEG3) {
        int r = i >> 10, k = i & 1023;
        int hh = r >> 7, cc = r & 127;
        W3p[i] = (cc < 121) ? (_Float16)W3[(size_t)(hh * 121 + cc) * 1024 + k] : (_Float16)0.f;
        return;
    }
    i -= SEG3;
    if (i < SEG4) {
        int hh = i >> 7, cc = i & 127;
        asp[i] = (cc < 121) ? as3[hh * 121 + cc] : 0.f;
        adp[i] = (cc < 121) ? ad3[hh * 121 + cc] : 0.f;
        return;
    }
    i -= SEG4;
    if (i < SEG5) xh[N_NODES * 1024 + i] = (_Float16)0.f;
}

// ---------------- fp16 MFMA GEMM with XCD-local row-panel mapping ----------------
__device__ __forceinline__ void gload_lds(const _Float16* g, _Float16* l) {
    __builtin_amdgcn_global_load_lds(
        (const __attribute__((address_space(1))) void*)g,
        (__attribute__((address_space(3))) void*)l, 16, 0, 0);
}

// grid: (8, 10*NXB). rb = bx + 8*(by/NXB) -> all blocks sharing an A-row-panel
// share bx, i.e. land on one XCD under flat%8 round-robin. rb>=79 blocks idle.
__global__ __launch_bounds__(256) void gemm_mfma(const _Float16* __restrict__ A,
                                                 const _Float16* __restrict__ B,
                                                 _Float16* __restrict__ C,
                                                 int M, int Nn, int Kp, int ldc) {
    const int NXB = gridDim.y / 10;
    const int rb  = blockIdx.x + 8 * (blockIdx.y / NXB);
    const int cb  = blockIdx.y % NXB;
    if (rb >= 79) return;
    __shared__ _Float16 lds[16384];
    const int tid  = threadIdx.x;
    const int bm   = rb * 128, bn = cb * 128;
    const int w    = tid >> 6, lane = tid & 63;
    const int wr   = w >> 1,   wc   = w & 1;
    const int la   = lane & 15, g = lane >> 4;

    f32x4 acc[4][4] = {};

    const int srow = tid >> 3;
    const int skb0 = (tid & 7) * 16;

    for (int k0 = 0; k0 < Kp; k0 += 64) {
        __syncthreads();
#pragma unroll
        for (int i = 0; i < 4; i++) {
            int row = i * 32 + srow;
            int kb  = skb0 ^ ((row & 7) << 4);
            gload_lds(A + (size_t)(bm + row) * Kp + k0 + (kb >> 1),
                      lds + i * 2048 + w * 512);
        }
#pragma unroll
        for (int i = 0; i < 4; i++) {
            int row = i * 32 + srow;
            int kb  = skb0 ^ ((row & 7) << 4);
            gload_lds(B + (size_t)(bn + row) * Kp + k0 + (kb >> 1),
                      lds + 8192 + i * 2048 + w * 512);
        }
        asm volatile("s_waitcnt vmcnt(0)");
        __syncthreads();
#pragma unroll
        for (int s = 0; s < 2; s++) {
            f16x8 af[4], bf[4];
#pragma unroll
            for (int m = 0; m < 4; m++) {
                int r  = wr * 64 + m * 16 + la;
                int bc = (s * 64 + g * 16) ^ ((r & 7) << 4);
                af[m] = *(const f16x8*)(lds + r * 64 + (bc >> 1));
            }
#pragma unroll
            for (int n = 0; n < 4; n++) {
                int r  = wc * 64 + n * 16 + la;
                int bc = (s * 64 + g * 16) ^ ((r & 7) << 4);
                bf[n] = *(const f16x8*)(lds + 8192 + r * 64 + (bc >> 1));
            }
#pragma unroll
            for (int m = 0; m < 4; m++)
#pragma unroll
                for (int n = 0; n < 4; n++)
                    acc[m][n] = __builtin_amdgcn_mfma_f32_16x16x32_f16(af[m], bf[n], acc[m][n], 0, 0, 0);
        }
    }
#pragma unroll
    for (int m = 0; m < 4; m++) {
#pragma unroll
        for (int n = 0; n < 4; n++) {
            int col = bn + wc * 64 + n * 16 + la;
            if (col >= Nn) continue;
#pragma unroll
            for (int r = 0; r < 4; r++) {
                int row = bm + wr * 64 + m * 16 + g * 4 + r;
                if (row < M) C[(size_t)row * ldc + col] = (_Float16)acc[m][n][r];
            }
        }
    }
}

// ---------------- attn for H=4, HC=1024: one wave per node ----------------
__global__ __launch_bounds__(256) void attn4(const _Float16* __restrict__ h,
        const float* __restrict__ a_s, const float* __restrict__ a_d,
        float* __restrict__ esrc, float* __restrict__ edst) {
    const int w = threadIdx.x >> 6, lane = threadIdx.x & 63;
    const int node = blockIdx.x * 4 + w;
    const _Float16* row = h + (size_t)node * 1024;
    float ps[4], pd[4];
#pragma unroll
    for (int j = 0; j < 4; j++) {
        int c0 = j * 256 + lane * 4;
        f16x4 v = *(const f16x4*)(row + c0);
        float4 sa = *(const float4*)(a_s + c0);
        float4 da = *(const float4*)(a_d + c0);
        ps[j] = (float)v[0] * sa.x + (float)v[1] * sa.y + (float)v[2] * sa.z + (float)v[3] * sa.w;
        pd[j] = (float)v[0] * da.x + (float)v[1] * da.y + (float)v[2] * da.z + (float)v[3] * da.w;
    }
#pragma unroll
    for (int j = 0; j < 4; j++) {
#pragma unroll
        for (int off = 32; off; off >>= 1) {
            ps[j] += __shfl_xor(ps[j], off);
            pd[j] += __shfl_xor(pd[j], off);
        }
    }
    if (lane == 0) {
        *(float4*)(esrc + (size_t)node * 4) = make_float4(ps[0], ps[1], ps[2], ps[3]);
        *(float4*)(edst + (size_t)node * 4) = make_float4(pd[0], pd[1], pd[2], pd[3]);
    }
}

// ---------------- attn for layer 3 (padded head stride 128): one wave per node ----------------
__global__ __launch_bounds__(256) void attn6(const _Float16* __restrict__ h,
        const float* __restrict__ asp, const float* __restrict__ adp,
        float* __restrict__ esrc, float* __restrict__ edst) {
    const int w = threadIdx.x >> 6, lane = threadIdx.x & 63;
    const int node = blockIdx.x * 4 + w;
    const _Float16* row = h + (size_t)node * 768;
    float ps[3], pd[3];
#pragma unroll
    for (int j = 0; j < 3; j++) {
        int c0 = j * 256 + lane * 4;   // head = 2j + (lane>=32)
        f16x4 v = *(const f16x4*)(row + c0);
        float4 sa = *(const float4*)(asp + c0);
        float4 da = *(const float4*)(adp + c0);
        ps[j] = (float)v[0] * sa.x + (float)v[1] * sa.y + (float)v[2] * sa.z + (float)v[3] * sa.w;
        pd[j] = (float)v[0] * da.x + (float)v[1] * da.y + (float)v[2] * da.z + (float)v[3] * da.w;
    }
#pragma unroll
    for (int j = 0; j < 3; j++) {
#pragma unroll
        for (int off = 16; off; off >>= 1) {
            ps[j] += __shfl_xor(ps[j], off);
            pd[j] += __shfl_xor(pd[j], off);
        }
    }
    if (lane == 0 || lane == 32) {
        int hb = lane >> 5;
        float* es = esrc + (size_t)node * 6;
        float* ed = edst + (size_t)node * 6;
#pragma unroll
        for (int j = 0; j < 3; j++) { es[2 * j + hb] = ps[j]; ed[2 * j + hb] = pd[j]; }
    }
}

// ---------------- softmax alphas: wave per dst, packed {alpha, src} per (edge,head) ----------------
template<int H>
__global__ __launch_bounds__(256) void alpha_kernel(const float* __restrict__ esrc,
        const float* __restrict__ edst, const int* __restrict__ rowptr,
        const int* __restrict__ perm, float2* __restrict__ apk) {
    const int w = threadIdx.x >> 6, lane = threadIdx.x & 63;
    const int d = blockIdx.x * 4 + w;
    int r0 = rowptr[d];
    int deg = rowptr[d + 1] - r0; if (deg > MAXDEG) deg = MAXDEG;
    float ed[H];
#pragma unroll
    for (int j = 0; j < H; j++) ed[j] = edst[(size_t)d * H + j];
    int s0 = 0, s1 = 0;
    float e0[H], e1[H];
    const bool a0v = lane < deg, a1v = lane + 64 < deg;
    if (a0v) {
        s0 = perm[r0 + lane];
        const float* pe = esrc + (size_t)s0 * H;
#pragma unroll
        for (int j = 0; j < H; j++) e0[j] = leaky(pe[j] + ed[j]);
    }
    if (a1v) {
        s1 = perm[r0 + lane + 64];
        const float* pe = esrc + (size_t)s1 * H;
#pragma unroll
        for (int j = 0; j < H; j++) e1[j] = leaky(pe[j] + ed[j]);
    }
#pragma unroll
    for (int j = 0; j < H; j++) {
        float m = fmaxf(a0v ? e0[j] : -1e30f, a1v ? e1[j] : -1e30f);
#pragma unroll
        for (int off = 32; off; off >>= 1) m = fmaxf(m, __shfl_xor(m, off));
        float x0 = a0v ? __expf(e0[j] - m) : 0.f;
        float x1 = a1v ? __expf(e1[j] - m) : 0.f;
        float ss = x0 + x1;
#pragma unroll
        for (int off = 32; off; off >>= 1) ss += __shfl_xor(ss, off);
        float inv = 1.f / fmaxf(ss, 1e-16f);
        e0[j] = x0 * inv; e1[j] = x1 * inv;
    }
    if (a0v) {
        float2* p = apk + (size_t)(r0 + lane) * H;
#pragma unroll
        for (int j = 0; j < H; j++) p[j] = make_float2(e0[j], __int_as_float(s0));
    }
    if (a1v) {
        float2* p = apk + (size_t)(r0 + lane + 64) * H;
#pragma unroll
        for (int j = 0; j < H; j++) p[j] = make_float2(e1[j], __int_as_float(s1));
    }
}

// ---------------- XCD-sliced gather (layers 1-2): slice s pinned to XCD s ----------------
// grid(8, N/4): wave w of block handles dst = by*4+w, cols [s*128, s*128+128)
template<int RES>
__global__ __launch_bounds__(256) void agg_slice(const _Float16* __restrict__ h,
        const float2* __restrict__ apk, const int* __restrict__ rowptr,
        const float* __restrict__ bias, _Float16* __restrict__ xh) {
    const int s = blockIdx.x;
    const int w = threadIdx.x >> 6, lane = threadIdx.x & 63;
    const int d = blockIdx.y * 4 + w;
    const int hh = s >> 1;
    const int col = s * 128 + lane * 2;
    int r0 = rowptr[d];
    int deg = rowptr[d + 1] - r0; if (deg > MAXDEG) deg = MAXDEG;
    float a0 = 0.f, a1 = 0.f;
    const float2* ap = apk + (size_t)r0 * 4 + hh;
#pragma unroll 4
    for (int t = 0; t < deg; t++) {
        float2 pa = ap[t * 4];
        int src = __float_as_int(pa.y);
        f16x2 v = *(const f16x2*)(h + (size_t)src * 1024 + col);
        a0 += pa.x * (float)v[0];
        a1 += pa.x * (float)v[1];
    }
    size_t o = (size_t)d * 1024 + col;
    float2 bv = *(const float2*)(bias + col);
    float rv0 = 0.f, rv1 = 0.f;
    if (RES) {
        f16x2 rv = *(const f16x2*)(xh + o);
        rv0 = (float)rv[0]; rv1 = (float)rv[1];
    }
    float v0 = a0 + bv.x + rv0;
    float v1 = a1 + bv.y + rv1;
    v0 = (v0 > 0.f) ? v0 : expm1f(v0);
    v1 = (v1 > 0.f) ? v1 : expm1f(v1);
    f16x2 hv; hv[0] = (_Float16)v0; hv[1] = (_Float16)v1;
    *(f16x2*)(xh + o) = hv;
}

// ---------------- XCD-sliced gather layer 3: 96-col slices -> f16 partials ----------------
__global__ __launch_bounds__(256) void agg_slice3(const _Float16* __restrict__ h,
        const float2* __restrict__ apk, const int* __restrict__ rowptr,
        _Float16* __restrict__ obuf) {
    const int s = blockIdx.x;
    const int w = threadIdx.x >> 6, lane = threadIdx.x & 63;
    if (lane >= 48) return;                  // 48 lanes x 2 cols = 96 cols
    const int d = blockIdx.y * 4 + w;
    const int col = s * 96 + lane * 2;
    const int hh = col >> 7;                 // padded head stride 128
    int r0 = rowptr[d];
    int deg = rowptr[d + 1] - r0; if (deg > MAXDEG) deg = MAXDEG;
    float a0 = 0.f, a1 = 0.f;
    const float2* ap = apk + (size_t)r0 * 6 + hh;
#pragma unroll 4
    for (int t = 0; t < deg; t++) {
        float2 pa = ap[t * 6];
        int src = __float_as_int(pa.y);
        f16x2 v = *(const f16x2*)(h + (size_t)src * 768 + col);
        a0 += pa.x * (float)v[0];
        a1 += pa.x * (float)v[1];
    }
    f16x2 hv; hv[0] = (_Float16)a0; hv[1] = (_Float16)a1;
    *(f16x2*)(obuf + (size_t)d * 768 + col) = hv;
}

// ---------------- final head-mean + bias + sigmoid ----------------
__global__ void finish_kernel(const _Float16* __restrict__ obuf,
                              const float* __restrict__ b3, float* __restrict__ out) {
    int i = blockIdx.x * 256 + threadIdx.x;
    if (i >= N_NODES * 121) return;
    int d = i / 121, cc = i - d * 121;
    float ssum = 0.f;
#pragma unroll
    for (int hh = 0; hh < 6; hh++) ssum += (float)obuf[(size_t)d * 768 + hh * 128 + cc];
    float sres = ssum * (1.f / 6.f) + b3[cc];
    out[i] = 1.f / (1.f + __expf(-sres));
}

// ---------------- launcher ----------------
extern "C" void kernel_launch(void* const* d_in, const int* in_sizes, int n_in,
                              void* d_out, int out_size, void* d_ws, size_t ws_size,
                              hipStream_t stream) {
    const float* x   = (const float*)d_in[0];
    const int*   ei  = (const int*)d_in[1];
    const float* W1  = (const float*)d_in[2];
    const float* as1 = (const float*)d_in[3];
    const float* ad1 = (const float*)d_in[4];
    const float* b1  = (const float*)d_in[5];
    const float* W2  = (const float*)d_in[6];
    const float* as2 = (const float*)d_in[7];
    const float* ad2 = (const float*)d_in[8];
    const float* b2  = (const float*)d_in[9];
    const float* W3  = (const float*)d_in[10];
    const float* as3 = (const float*)d_in[11];
    const float* ad3 = (const float*)d_in[12];
    const float* b3  = (const float*)d_in[13];
    float* out = (float*)d_out;

    float* fws  = (float*)d_ws;
    float* esrc = fws;                      // N*6 (stride 4 or 6 by layer)
    float* edst = fws + 60000;              // N*6
    float* asp  = fws + 120000;             // 768
    float* adp  = fws + 120768;             // 768
    float2* apk = (float2*)(fws + 121536);  // 170000*6 float2
    int*   iws  = (int*)(fws + 121536 + 2040000);
    int* deg    = iws;                      // N
    int* rowptr = iws + N_NODES;            // N+1
    int* cursor = iws + 2 * N_NODES + 1;    // N
    int* perm   = iws + 3 * N_NODES + 1;    // E_TOT
    _Float16* f16b = (_Float16*)(iws + 3 * N_NODES + 1 + E_TOT + 3);
    _Float16* xh   = f16b;                          // MPAD*1024
    _Float16* xh1  = xh + (size_t)MPAD * 1024;      // MPAD*64
    _Float16* W1h  = xh1 + (size_t)MPAD * 64;       // 1024*64
    _Float16* W2h  = W1h + 1024 * 64;               // 1024*1024
    _Float16* W3p  = W2h + 1024 * 1024;             // 768*1024 (head-padded)
    _Float16* h16  = W3p + 768 * 1024;              // MPAD*1024
    _Float16* obuf = h16 + (size_t)MPAD * 1024;     // N*768

    hipMemsetAsync(deg, 0, N_NODES * sizeof(int), stream);
    count_kernel<<<(E_TOT + 255) / 256, 256, 0, stream>>>(ei, deg);
    scan_kernel<<<1, 1024, 0, stream>>>(deg, rowptr, cursor);
    scatter_kernel<<<(E_TOT + 255) / 256, 256, 0, stream>>>(ei, cursor, perm);

    dim3 blk(256);
    cvt_all<<<(CVT_TOTAL + 255) / 256, blk, 0, stream>>>(x, W1, W2, W3, as3, ad3,
                                                          xh1, W1h, W2h, W3p, asp, adp, xh);

    // ---- layer 1: K=50->64, H=4, C=256 ----
    {
        gemm_mfma<<<dim3(8, 80), blk, 0, stream>>>(xh1, W1h, h16, N_NODES, 1024, 64, 1024);
        attn4<<<N_NODES / 4, blk, 0, stream>>>(h16, as1, ad1, esrc, edst);
        alpha_kernel<4><<<N_NODES / 4, blk, 0, stream>>>(esrc, edst, rowptr, perm, apk);
        agg_slice<0><<<dim3(8, N_NODES / 4), blk, 0, stream>>>(h16, apk, rowptr, b1, xh);
    }
    // ---- layer 2: K=1024, H=4, C=256, residual ----
    {
        gemm_mfma<<<dim3(8, 80), blk, 0, stream>>>(xh, W2h, h16, N_NODES, 1024, 1024, 1024);
        attn4<<<N_NODES / 4, blk, 0, stream>>>(h16, as2, ad2, esrc, edst);
        alpha_kernel<4><<<N_NODES / 4, blk, 0, stream>>>(esrc, edst, rowptr, perm, apk);
        agg_slice<1><<<dim3(8, N_NODES / 4), blk, 0, stream>>>(h16, apk, rowptr, b2, xh);
    }
    // ---- layer 3: K=1024, H=6, C=121 (padded 128), mean heads + sigmoid ----
    {
        gemm_mfma<<<dim3(8, 60), blk, 0, stream>>>(xh, W3p, h16, N_NODES, 768, 1024, 768);
        attn6<<<N_NODES / 4, blk, 0, stream>>>(h16, asp, adp, esrc, edst);
        alpha_kernel<6><<<N_NODES / 4, blk, 0, stream>>>(esrc, edst, rowptr, perm, apk);
        agg_slice3<<<dim3(8, N_NODES / 4), blk, 0, stream>>>(h16, apk, rowptr, obuf);
        finish_kernel<<<(N_NODES * 121 + 255) / 256, blk, 0, stream>>>(obuf, b3, out);
    }
}

// Round 9
// 304.945 us; speedup vs baseline: 1.2144x; 1.2144x over previous
//
#include <hip/hip_runtime.h>
#include <math.h>

#define N_NODES 10000
#define E_EDGES 160000
#define E_TOT   170000   // E + self loops
#define MAXDEG  128
#define MPAD    10112    // 79 * 128

typedef _Float16 f16x8 __attribute__((ext_vector_type(8)));
typedef _Float16 f16x4 __attribute__((ext_vector_type(4)));
typedef float    f32x4 __attribute__((ext_vector_type(4)));

__device__ __forceinline__ float leaky(float e) { return (e > 0.f) ? e : 0.2f * e; }

__device__ __forceinline__ unsigned int pack_as(float a, int s) {
    union { _Float16 h; unsigned short u; } cv;
    cv.h = (_Float16)a;
    return (unsigned int)(unsigned short)s | ((unsigned int)cv.u << 16);
}

// ---------------- graph CSR build (by dst) ----------------
__global__ void count_kernel(const int* __restrict__ ei, int* __restrict__ deg) {
    int e = blockIdx.x * 256 + threadIdx.x;
    if (e >= E_TOT) return;
    int dst = (e < E_EDGES) ? ei[E_EDGES + e] : (e - E_EDGES);
    atomicAdd(&deg[dst], 1);
}

__global__ void scan_kernel(const int* __restrict__ deg, int* __restrict__ rowptr,
                            int* __restrict__ cursor) {
    __shared__ int sums[1024];
    int t = threadIdx.x;
    const int CH = (N_NODES + 1023) / 1024;
    int base = t * CH;
    int s = 0;
    for (int j = 0; j < CH; j++) { int i = base + j; if (i < N_NODES) s += deg[i]; }
    sums[t] = s; __syncthreads();
    for (int off = 1; off < 1024; off <<= 1) {
        int v = (t >= off) ? sums[t - off] : 0;
        __syncthreads();
        sums[t] += v;
        __syncthreads();
    }
    int excl = (t == 0) ? 0 : sums[t - 1];
    for (int j = 0; j < CH; j++) {
        int i = base + j;
        if (i < N_NODES) { rowptr[i] = excl; cursor[i] = excl; excl += deg[i]; }
    }
    if (t == 1023) rowptr[N_NODES] = sums[1023];
}

__global__ void scatter_kernel(const int* __restrict__ ei, int* __restrict__ cursor,
                               int* __restrict__ perm_src) {
    int e = blockIdx.x * 256 + threadIdx.x;
    if (e >= E_TOT) return;
    int src, dst;
    if (e < E_EDGES) { src = ei[e]; dst = ei[E_EDGES + e]; }
    else { src = e - E_EDGES; dst = src; }
    int pos = atomicAdd(&cursor[dst], 1);
    perm_src[pos] = src;
}

// ---------------- all conversions / padding in one kernel ----------------
#define SEG0 (MPAD * 64)               // xh1
#define SEG1 (1024 * 64)               // W1h
#define SEG2 (1024 * 1024)             // W2h
#define SEG3 (768 * 1024)              // W3p (head-padded rows)
#define SEG4 768                        // asp/adp
#define SEG5 ((MPAD - N_NODES) * 1024) // xh zero tail
#define CVT_TOTAL (SEG0 + SEG1 + SEG2 + SEG3 + SEG4 + SEG5)

__global__ void cvt_all(const float* __restrict__ x, const float* __restrict__ W1,
                        const float* __restrict__ W2, const float* __restrict__ W3,
                        const float* __restrict__ as3, const float* __restrict__ ad3,
                        _Float16* __restrict__ xh1, _Float16* __restrict__ W1h,
                        _Float16* __restrict__ W2h, _Float16* __restrict__ W3p,
                        float* __restrict__ asp, float* __restrict__ adp,
                        _Float16* __restrict__ xh) {
    int i = blockIdx.x * 256 + threadIdx.x;
    if (i < SEG0) {
        int r = i >> 6, c = i & 63;
        xh1[i] = (r < N_NODES && c < 50) ? (_Float16)x[r * 50 + c] : (_Float16)0.f;
        return;
    }
    i -= SEG0;
    if (i < SEG1) {
        int r = i >> 6, c = i & 63;
        W1h[i] = (c < 50) ? (_Float16)W1[r * 50 + c] : (_Float16)0.f;
        return;
    }
    i -= SEG1;
    if (i < SEG2) { W2h[i] = (_Float16)W2[i]; return; }
    i -= SEG2;
    if (i < SEG3) {
        int r = i >> 10, k = i & 1023;
        int hh = r >> 7, cc = r & 127;
        W3p[i] = (cc < 121) ? (_Float16)W3[(size_t)(hh * 121 + cc) * 1024 + k] : (_Float16)0.f;
        return;
    }
    i -= SEG3;
    if (i < SEG4) {
        int hh = i >> 7, cc = i & 127;
        asp[i] = (cc < 121) ? as3[hh * 121 + cc] : 0.f;
        adp[i] = (cc < 121) ? ad3[hh * 121 + cc] : 0.f;
        return;
    }
    i -= SEG4;
    if (i < SEG5) xh[N_NODES * 1024 + i] = (_Float16)0.f;
}

// ---------------- fp16 MFMA GEMM with XCD-local row-panel mapping ----------------
__device__ __forceinline__ void gload_lds(const _Float16* g, _Float16* l) {
    __builtin_amdgcn_global_load_lds(
        (const __attribute__((address_space(1))) void*)g,
        (__attribute__((address_space(3))) void*)l, 16, 0, 0);
}

// grid: (8, 10*NXB). rb = bx + 8*(by/NXB) -> all blocks sharing an A-row-panel
// share bx, i.e. land on one XCD under flat%8 round-robin. rb>=79 blocks idle.
__global__ __launch_bounds__(256) void gemm_mfma(const _Float16* __restrict__ A,
                                                 const _Float16* __restrict__ B,
                                                 _Float16* __restrict__ C,
                                                 int M, int Nn, int Kp, int ldc) {
    const int NXB = gridDim.y / 10;
    const int rb  = blockIdx.x + 8 * (blockIdx.y / NXB);
    const int cb  = blockIdx.y % NXB;
    if (rb >= 79) return;
    __shared__ _Float16 lds[16384];
    const int tid  = threadIdx.x;
    const int bm   = rb * 128, bn = cb * 128;
    const int w    = tid >> 6, lane = tid & 63;
    const int wr   = w >> 1,   wc   = w & 1;
    const int la   = lane & 15, g = lane >> 4;

    f32x4 acc[4][4] = {};

    const int srow = tid >> 3;
    const int skb0 = (tid & 7) * 16;

    for (int k0 = 0; k0 < Kp; k0 += 64) {
        __syncthreads();
#pragma unroll
        for (int i = 0; i < 4; i++) {
            int row = i * 32 + srow;
            int kb  = skb0 ^ ((row & 7) << 4);
            gload_lds(A + (size_t)(bm + row) * Kp + k0 + (kb >> 1),
                      lds + i * 2048 + w * 512);
        }
#pragma unroll
        for (int i = 0; i < 4; i++) {
            int row = i * 32 + srow;
            int kb  = skb0 ^ ((row & 7) << 4);
            gload_lds(B + (size_t)(bn + row) * Kp + k0 + (kb >> 1),
                      lds + 8192 + i * 2048 + w * 512);
        }
        asm volatile("s_waitcnt vmcnt(0)");
        __syncthreads();
#pragma unroll
        for (int s = 0; s < 2; s++) {
            f16x8 af[4], bf[4];
#pragma unroll
            for (int m = 0; m < 4; m++) {
                int r  = wr * 64 + m * 16 + la;
                int bc = (s * 64 + g * 16) ^ ((r & 7) << 4);
                af[m] = *(const f16x8*)(lds + r * 64 + (bc >> 1));
            }
#pragma unroll
            for (int n = 0; n < 4; n++) {
                int r  = wc * 64 + n * 16 + la;
                int bc = (s * 64 + g * 16) ^ ((r & 7) << 4);
                bf[n] = *(const f16x8*)(lds + 8192 + r * 64 + (bc >> 1));
            }
#pragma unroll
            for (int m = 0; m < 4; m++)
#pragma unroll
                for (int n = 0; n < 4; n++)
                    acc[m][n] = __builtin_amdgcn_mfma_f32_16x16x32_f16(af[m], bf[n], acc[m][n], 0, 0, 0);
        }
    }
#pragma unroll
    for (int m = 0; m < 4; m++) {
#pragma unroll
        for (int n = 0; n < 4; n++) {
            int col = bn + wc * 64 + n * 16 + la;
            if (col >= Nn) continue;
#pragma unroll
            for (int r = 0; r < 4; r++) {
                int row = bm + wr * 64 + m * 16 + g * 4 + r;
                if (row < M) C[(size_t)row * ldc + col] = (_Float16)acc[m][n][r];
            }
        }
    }
}

// ---------------- attn for H=4, HC=1024: one wave per node ----------------
__global__ __launch_bounds__(256) void attn4(const _Float16* __restrict__ h,
        const float* __restrict__ a_s, const float* __restrict__ a_d,
        float* __restrict__ esrc, float* __restrict__ edst) {
    const int w = threadIdx.x >> 6, lane = threadIdx.x & 63;
    const int node = blockIdx.x * 4 + w;
    const _Float16* row = h + (size_t)node * 1024;
    float ps[4], pd[4];
#pragma unroll
    for (int j = 0; j < 4; j++) {
        int c0 = j * 256 + lane * 4;
        f16x4 v = *(const f16x4*)(row + c0);
        float4 sa = *(const float4*)(a_s + c0);
        float4 da = *(const float4*)(a_d + c0);
        ps[j] = (float)v[0] * sa.x + (float)v[1] * sa.y + (float)v[2] * sa.z + (float)v[3] * sa.w;
        pd[j] = (float)v[0] * da.x + (float)v[1] * da.y + (float)v[2] * da.z + (float)v[3] * da.w;
    }
#pragma unroll
    for (int j = 0; j < 4; j++) {
#pragma unroll
        for (int off = 32; off; off >>= 1) {
            ps[j] += __shfl_xor(ps[j], off);
            pd[j] += __shfl_xor(pd[j], off);
        }
    }
    if (lane == 0) {
        *(float4*)(esrc + (size_t)node * 4) = make_float4(ps[0], ps[1], ps[2], ps[3]);
        *(float4*)(edst + (size_t)node * 4) = make_float4(pd[0], pd[1], pd[2], pd[3]);
    }
}

// ---------------- attn for layer 3 (padded head stride 128): one wave per node ----------------
__global__ __launch_bounds__(256) void attn6(const _Float16* __restrict__ h,
        const float* __restrict__ asp, const float* __restrict__ adp,
        float* __restrict__ esrc, float* __restrict__ edst) {
    const int w = threadIdx.x >> 6, lane = threadIdx.x & 63;
    const int node = blockIdx.x * 4 + w;
    const _Float16* row = h + (size_t)node * 768;
    float ps[3], pd[3];
#pragma unroll
    for (int j = 0; j < 3; j++) {
        int c0 = j * 256 + lane * 4;   // head = 2j + (lane>=32)
        f16x4 v = *(const f16x4*)(row + c0);
        float4 sa = *(const float4*)(asp + c0);
        float4 da = *(const float4*)(adp + c0);
        ps[j] = (float)v[0] * sa.x + (float)v[1] * sa.y + (float)v[2] * sa.z + (float)v[3] * sa.w;
        pd[j] = (float)v[0] * da.x + (float)v[1] * da.y + (float)v[2] * da.z + (float)v[3] * da.w;
    }
#pragma unroll
    for (int j = 0; j < 3; j++) {
#pragma unroll
        for (int off = 16; off; off >>= 1) {
            ps[j] += __shfl_xor(ps[j], off);
            pd[j] += __shfl_xor(pd[j], off);
        }
    }
    if (lane == 0 || lane == 32) {
        int hb = lane >> 5;
        float* es = esrc + (size_t)node * 6;
        float* ed = edst + (size_t)node * 6;
#pragma unroll
        for (int j = 0; j < 3; j++) { es[2 * j + hb] = ps[j]; ed[2 * j + hb] = pd[j]; }
    }
}

// ---------------- softmax alphas: wave per dst, SoA packed {src:u16, alpha:f16} ----------------
template<int H>
__global__ __launch_bounds__(256) void alpha_kernel(const float* __restrict__ esrc,
        const float* __restrict__ edst, const int* __restrict__ rowptr,
        const int* __restrict__ perm, unsigned int* __restrict__ pack) {
    const int w = threadIdx.x >> 6, lane = threadIdx.x & 63;
    const int d = blockIdx.x * 4 + w;
    int r0 = rowptr[d];
    int deg = rowptr[d + 1] - r0; if (deg > MAXDEG) deg = MAXDEG;
    float ed[H];
#pragma unroll
    for (int j = 0; j < H; j++) ed[j] = edst[(size_t)d * H + j];
    int s0 = 0, s1 = 0;
    float e0[H], e1[H];
    const bool a0v = lane < deg, a1v = lane + 64 < deg;
    if (a0v) {
        s0 = perm[r0 + lane];
        const float* pe = esrc + (size_t)s0 * H;
#pragma unroll
        for (int j = 0; j < H; j++) e0[j] = leaky(pe[j] + ed[j]);
    }
    if (a1v) {
        s1 = perm[r0 + lane + 64];
        const float* pe = esrc + (size_t)s1 * H;
#pragma unroll
        for (int j = 0; j < H; j++) e1[j] = leaky(pe[j] + ed[j]);
    }
#pragma unroll
    for (int j = 0; j < H; j++) {
        float m = fmaxf(a0v ? e0[j] : -1e30f, a1v ? e1[j] : -1e30f);
#pragma unroll
        for (int off = 32; off; off >>= 1) m = fmaxf(m, __shfl_xor(m, off));
        float x0 = a0v ? __expf(e0[j] - m) : 0.f;
        float x1 = a1v ? __expf(e1[j] - m) : 0.f;
        float ss = x0 + x1;
#pragma unroll
        for (int off = 32; off; off >>= 1) ss += __shfl_xor(ss, off);
        float inv = 1.f / fmaxf(ss, 1e-16f);
        e0[j] = x0 * inv; e1[j] = x1 * inv;
    }
    if (a0v) {
#pragma unroll
        for (int j = 0; j < H; j++) pack[(size_t)j * E_TOT + r0 + lane] = pack_as(e0[j], s0);
    }
    if (a1v) {
#pragma unroll
        for (int j = 0; j < H; j++) pack[(size_t)j * E_TOT + r0 + lane + 64] = pack_as(e1[j], s1);
    }
}

// ---------------- XCD-sliced gather (layers 1-2): slice s pinned to XCD s ----------------
// grid(8, 1250): wave = 2 dsts x 32 lanes x f16x4; no LDS.
template<int RES>
__global__ __launch_bounds__(256) void agg_slice2(const _Float16* __restrict__ h,
        const unsigned int* __restrict__ pack, const int* __restrict__ rowptr,
        const float* __restrict__ bias, _Float16* __restrict__ xh) {
    const int s = blockIdx.x;
    const int w = threadIdx.x >> 6, lane = threadIdx.x & 63;
    const int d = blockIdx.y * 8 + w * 2 + (lane >> 5);
    const int col = s * 128 + (lane & 31) * 4;
    const int hh = s >> 1;
    int r0 = rowptr[d];
    int deg = rowptr[d + 1] - r0; if (deg > MAXDEG) deg = MAXDEG;
    const unsigned int* pp = pack + (size_t)hh * E_TOT + r0;
    f32x4 acc = {};
#pragma unroll 4
    for (int t = 0; t < deg; t++) {
        unsigned int p = pp[t];
        int src = p & 0xFFFF;
        union { unsigned short u; _Float16 hf; } cv; cv.u = (unsigned short)(p >> 16);
        float a = (float)cv.hf;
        f16x4 v = *(const f16x4*)(h + (size_t)src * 1024 + col);
        acc[0] += a * (float)v[0]; acc[1] += a * (float)v[1];
        acc[2] += a * (float)v[2]; acc[3] += a * (float)v[3];
    }
    size_t o = (size_t)d * 1024 + col;
    float4 bv = *(const float4*)(bias + col);
    float r0v = 0.f, r1v = 0.f, r2v = 0.f, r3v = 0.f;
    if (RES) {
        f16x4 rv = *(const f16x4*)(xh + o);
        r0v = (float)rv[0]; r1v = (float)rv[1]; r2v = (float)rv[2]; r3v = (float)rv[3];
    }
    float v0 = acc[0] + bv.x + r0v;
    float v1 = acc[1] + bv.y + r1v;
    float v2 = acc[2] + bv.z + r2v;
    float v3 = acc[3] + bv.w + r3v;
    v0 = (v0 > 0.f) ? v0 : expm1f(v0);
    v1 = (v1 > 0.f) ? v1 : expm1f(v1);
    v2 = (v2 > 0.f) ? v2 : expm1f(v2);
    v3 = (v3 > 0.f) ? v3 : expm1f(v3);
    f16x4 hv; hv[0] = (_Float16)v0; hv[1] = (_Float16)v1; hv[2] = (_Float16)v2; hv[3] = (_Float16)v3;
    *(f16x4*)(xh + o) = hv;
}

// ---------------- layer-3 sliced gather: 6 head slices of 128 padded cols ----------------
__global__ __launch_bounds__(256) void agg_slice3(const _Float16* __restrict__ h,
        const unsigned int* __restrict__ pack, const int* __restrict__ rowptr,
        _Float16* __restrict__ obuf) {
    const int s = blockIdx.x;               // == head
    const int w = threadIdx.x >> 6, lane = threadIdx.x & 63;
    const int d = blockIdx.y * 8 + w * 2 + (lane >> 5);
    const int col = s * 128 + (lane & 31) * 4;
    int r0 = rowptr[d];
    int deg = rowptr[d + 1] - r0; if (deg > MAXDEG) deg = MAXDEG;
    const unsigned int* pp = pack + (size_t)s * E_TOT + r0;
    f32x4 acc = {};
#pragma unroll 4
    for (int t = 0; t < deg; t++) {
        unsigned int p = pp[t];
        int src = p & 0xFFFF;
        union { unsigned short u; _Float16 hf; } cv; cv.u = (unsigned short)(p >> 16);
        float a = (float)cv.hf;
        f16x4 v = *(const f16x4*)(h + (size_t)src * 768 + col);
        acc[0] += a * (float)v[0]; acc[1] += a * (float)v[1];
        acc[2] += a * (float)v[2]; acc[3] += a * (float)v[3];
    }
    f16x4 hv; hv[0] = (_Float16)acc[0]; hv[1] = (_Float16)acc[1];
    hv[2] = (_Float16)acc[2]; hv[3] = (_Float16)acc[3];
    *(f16x4*)(obuf + (size_t)d * 768 + col) = hv;
}

// ---------------- final head-mean + bias + sigmoid ----------------
__global__ void finish_kernel(const _Float16* __restrict__ obuf,
                              const float* __restrict__ b3, float* __restrict__ out) {
    int i = blockIdx.x * 256 + threadIdx.x;
    if (i >= N_NODES * 121) return;
    int d = i / 121, cc = i - d * 121;
    float ssum = 0.f;
#pragma unroll
    for (int hh = 0; hh < 6; hh++) ssum += (float)obuf[(size_t)d * 768 + hh * 128 + cc];
    float sres = ssum * (1.f / 6.f) + b3[cc];
    out[i] = 1.f / (1.f + __expf(-sres));
}

// ---------------- launcher ----------------
extern "C" void kernel_launch(void* const* d_in, const int* in_sizes, int n_in,
                              void* d_out, int out_size, void* d_ws, size_t ws_size,
                              hipStream_t stream) {
    const float* x   = (const float*)d_in[0];
    const int*   ei  = (const int*)d_in[1];
    const float* W1  = (const float*)d_in[2];
    const float* as1 = (const float*)d_in[3];
    const float* ad1 = (const float*)d_in[4];
    const float* b1  = (const float*)d_in[5];
    const float* W2  = (const float*)d_in[6];
    const float* as2 = (const float*)d_in[7];
    const float* ad2 = (const float*)d_in[8];
    const float* b2  = (const float*)d_in[9];
    const float* W3  = (const float*)d_in[10];
    const float* as3 = (const float*)d_in[11];
    const float* ad3 = (const float*)d_in[12];
    const float* b3  = (const float*)d_in[13];
    float* out = (float*)d_out;

    float* fws  = (float*)d_ws;
    float* esrc = fws;                       // N*6
    float* edst = fws + 60000;               // N*6
    float* asp  = fws + 120000;              // 768
    float* adp  = fws + 120768;              // 768
    unsigned int* pack = (unsigned int*)(fws + 121536);  // 6 * E_TOT u32
    int*   iws  = (int*)(fws + 121536 + 6 * E_TOT);
    int* deg    = iws;                       // N
    int* rowptr = iws + N_NODES;             // N+1
    int* cursor = iws + 2 * N_NODES + 1;     // N
    int* perm   = iws + 3 * N_NODES + 1;     // E_TOT
    _Float16* f16b = (_Float16*)(iws + 3 * N_NODES + 1 + E_TOT + 3);
    _Float16* xh   = f16b;                          // MPAD*1024
    _Float16* xh1  = xh + (size_t)MPAD * 1024;      // MPAD*64
    _Float16* W1h  = xh1 + (size_t)MPAD * 64;       // 1024*64
    _Float16* W2h  = W1h + 1024 * 64;               // 1024*1024
    _Float16* W3p  = W2h + 1024 * 1024;             // 768*1024 (head-padded)
    _Float16* h16  = W3p + 768 * 1024;              // MPAD*1024
    _Float16* obuf = h16 + (size_t)MPAD * 1024;     // N*768

    hipMemsetAsync(deg, 0, N_NODES * sizeof(int), stream);
    count_kernel<<<(E_TOT + 255) / 256, 256, 0, stream>>>(ei, deg);
    scan_kernel<<<1, 1024, 0, stream>>>(deg, rowptr, cursor);
    scatter_kernel<<<(E_TOT + 255) / 256, 256, 0, stream>>>(ei, cursor, perm);

    dim3 blk(256);
    cvt_all<<<(CVT_TOTAL + 255) / 256, blk, 0, stream>>>(x, W1, W2, W3, as3, ad3,
                                                          xh1, W1h, W2h, W3p, asp, adp, xh);

    // ---- layer 1: K=50->64, H=4, C=256 ----
    {
        gemm_mfma<<<dim3(8, 80), blk, 0, stream>>>(xh1, W1h, h16, N_NODES, 1024, 64, 1024);
        attn4<<<N_NODES / 4, blk, 0, stream>>>(h16, as1, ad1, esrc, edst);
        alpha_kernel<4><<<N_NODES / 4, blk, 0, stream>>>(esrc, edst, rowptr, perm, pack);
        agg_slice2<0><<<dim3(8, N_NODES / 8), blk, 0, stream>>>(h16, pack, rowptr, b1, xh);
    }
    // ---- layer 2: K=1024, H=4, C=256, residual ----
    {
        gemm_mfma<<<dim3(8, 80), blk, 0, stream>>>(xh, W2h, h16, N_NODES, 1024, 1024, 1024);
        attn4<<<N_NODES / 4, blk, 0, stream>>>(h16, as2, ad2, esrc, edst);
        alpha_kernel<4><<<N_NODES / 4, blk, 0, stream>>>(esrc, edst, rowptr, perm, pack);
        agg_slice2<1><<<dim3(8, N_NODES / 8), blk, 0, stream>>>(h16, pack, rowptr, b2, xh);
    }
    // ---- layer 3: K=1024, H=6, C=121 (padded 128), mean heads + sigmoid ----
    {
        gemm_mfma<<<dim3(8, 60), blk, 0, stream>>>(xh, W3p, h16, N_NODES, 768, 1024, 768);
        attn6<<<N_NODES / 4, blk, 0, stream>>>(h16, asp, adp, esrc, edst);
        alpha_kernel<6><<<N_NODES / 4, blk, 0, stream>>>(esrc, edst, rowptr, perm, pack);
        agg_slice3<<<dim3(6, N_NODES / 8), blk, 0, stream>>>(h16, pack, rowptr, obuf);
        finish_kernel<<<(N_NODES * 121 + 255) / 256, blk, 0, stream>>>(obuf, b3, out);
    }
}